// Round 2
// baseline (194.612 us; speedup 1.0000x reference)
//
#include <hip/hip_runtime.h>

// Problem: B=16, PATCH_NUM=32, PATCH_SIZE=128, H=8, E=64, WIN=4096
// out[b,l,h,e] = V_inter[b, l>>7, h, e] + V_intra[b, l>>5, h, e]
// V_* are full-softmax attentions (scale = 1/8) over L=32 / L=128.
//
// Structure (round 1 -> 2): the fused kernel had 92.6 KB LDS -> 1 block/CU
// and gap-ridden duplicated stores; split into attention kernels (small
// writes) + a dedicated perfectly-coalesced upsample-add sweep.

#define NH 8
#define NE 64
#define ROWSTRIDE (NH * NE)   // 512 floats between consecutive l for fixed (b,h)

__device__ __forceinline__ float dot4(const float4 a, const float4 b) {
    return a.x * b.x + a.y * b.y + a.z * b.z + a.w * b.w;
}

// One block = (b, h, tile-of-32-query-rows), 256 threads.
// Writes its 32 attention-output rows to dst[B, L, H, E] (compact, no upsample).
template <int L>
__global__ __launch_bounds__(256) void attn_kernel(
    const float* __restrict__ qg_, const float* __restrict__ kg_,
    const float* __restrict__ vg_, float* __restrict__ dst)
{
    constexpr int TILES = L / 32;   // row tiles per (b,h)
    constexpr int CPT   = L / 32;   // score cols per thread
    constexpr int SST   = L + 1;    // score row stride (conflict-free)
    constexpr int KST   = 68;       // K/V/Q row stride (float4-aligned padding)

    __shared__ __align__(16) float Ks[L * KST];
    __shared__ __align__(16) float Vs[L * KST];
    __shared__ __align__(16) float Qs[32 * KST];
    __shared__ float S[32 * SST];

    const int tid  = threadIdx.x;
    const int bid  = blockIdx.x;
    const int tile = bid % TILES;
    const int h    = (bid / TILES) % NH;
    const int b    = bid / (TILES * NH);
    const int r0   = tile * 32;

    const float* kg = kg_ + ((size_t)b * L * NH + h) * NE;
    const float* vg = vg_ + ((size_t)b * L * NH + h) * NE;
    const float* qg = qg_ + ((size_t)(b * L + r0) * NH + h) * NE;

    // ---- stage K, V (all L rows) and Q (32 rows) into LDS ----
    for (int idx = tid; idx < L * 16; idx += 256) {
        const int row = idx >> 4;
        const int f   = (idx & 15) * 4;
        *(float4*)&Ks[row * KST + f] = *(const float4*)(kg + (size_t)row * ROWSTRIDE + f);
        *(float4*)&Vs[row * KST + f] = *(const float4*)(vg + (size_t)row * ROWSTRIDE + f);
    }
    for (int idx = tid; idx < 32 * 16; idx += 256) {
        const int row = idx >> 4;
        const int f   = (idx & 15) * 4;
        *(float4*)&Qs[row * KST + f] = *(const float4*)(qg + (size_t)row * ROWSTRIDE + f);
    }
    __syncthreads();

    // ---- scores: 32 rows x L cols, thread = 4 rows x CPT cols ----
    {
        const int rg = tid >> 5;        // 0..7 -> rows rg*4..rg*4+3
        const int cg = tid & 31;        // cols cg*CPT..cg*CPT+CPT-1
        const int rr = rg * 4;
        const int c0 = cg * CPT;
        float acc[4][CPT];
        #pragma unroll
        for (int i = 0; i < 4; i++)
            #pragma unroll
            for (int j = 0; j < CPT; j++) acc[i][j] = 0.f;

        #pragma unroll
        for (int e = 0; e < NE; e += 4) {
            float4 qv[4], kv[CPT];
            #pragma unroll
            for (int i = 0; i < 4; i++) qv[i] = *(const float4*)&Qs[(rr + i) * KST + e];
            #pragma unroll
            for (int j = 0; j < CPT; j++) kv[j] = *(const float4*)&Ks[(c0 + j) * KST + e];
            #pragma unroll
            for (int i = 0; i < 4; i++)
                #pragma unroll
                for (int j = 0; j < CPT; j++)
                    acc[i][j] += dot4(qv[i], kv[j]);
        }
        #pragma unroll
        for (int i = 0; i < 4; i++)
            #pragma unroll
            for (int j = 0; j < CPT; j++)
                S[(rr + i) * SST + c0 + j] = acc[i][j] * 0.125f;  // 1/sqrt(64)
    }
    __syncthreads();

    // ---- softmax: thread (r = tid>>3, sub = tid&7); redundant row scans ----
    const int r   = tid >> 3;
    const int sub = tid & 7;
    float m = -1e30f;
    for (int c = 0; c < L; c++) m = fmaxf(m, S[r * SST + c]);
    float sum = 0.f;
    for (int c = 0; c < L; c++) sum += __expf(S[r * SST + c] - m);
    const float inv = 1.f / sum;
    __syncthreads();              // everyone done reading raw scores
    for (int c = sub; c < L; c += 8)
        S[r * SST + c] = __expf(S[r * SST + c] - m);   // unnormalized p
    __syncthreads();

    // ---- PV: thread (r, sub) computes out[r][e0..e0+7] ----
    const int e0 = sub * 8;
    float a0=0,a1=0,a2=0,a3=0,a4=0,a5=0,a6=0,a7=0;
    for (int c = 0; c < L; c++) {
        const float p  = S[r * SST + c];
        const float4 va = *(const float4*)&Vs[c * KST + e0];
        const float4 vb = *(const float4*)&Vs[c * KST + e0 + 4];
        a0 += p * va.x; a1 += p * va.y; a2 += p * va.z; a3 += p * va.w;
        a4 += p * vb.x; a5 += p * vb.y; a6 += p * vb.z; a7 += p * vb.w;
    }
    const float4 oA = make_float4(a0 * inv, a1 * inv, a2 * inv, a3 * inv);
    const float4 oB = make_float4(a4 * inv, a5 * inv, a6 * inv, a7 * inv);

    float* w = dst + ((size_t)(b * L + r0 + r) * NH + h) * NE + e0;
    *(float4*)w       = oA;
    *(float4*)(w + 4) = oB;
}

// out[b,l,h,e] = wsInter[b, l>>7, h, e] + wsIntra[b, l>>5, h, e]
// One float4 per thread iteration; writes are fully coalesced (1 KB/wave).
// Reads hit L2/L3: total ws working set is 5 MiB with 128x/32x reuse.
__global__ __launch_bounds__(256) void upsample_add_kernel(
    const float4* __restrict__ wsI, const float4* __restrict__ wsT,
    float4* __restrict__ out)
{
    const int total = 16 * 4096 * NH * (NE / 4);   // 8,388,608 float4s
    int t = blockIdx.x * 256 + threadIdx.x;
    const int stride = gridDim.x * 256;
    for (; t < total; t += stride) {
        const int e4 = t & 15;
        const int h  = (t >> 4) & 7;
        const int l  = (t >> 7) & 4095;
        const int b  = t >> 19;
        const float4 a = wsI[((b * 32  + (l >> 7)) * NH + h) * 16 + e4];
        const float4 c = wsT[((b * 128 + (l >> 5)) * NH + h) * 16 + e4];
        out[t] = make_float4(a.x + c.x, a.y + c.y, a.z + c.z, a.w + c.w);
    }
}

extern "C" void kernel_launch(void* const* d_in, const int* in_sizes, int n_in,
                              void* d_out, int out_size, void* d_ws, size_t ws_size,
                              hipStream_t stream) {
    const float* q_inter = (const float*)d_in[0];
    const float* k_inter = (const float*)d_in[1];
    const float* v_inter = (const float*)d_in[2];
    const float* q_intra = (const float*)d_in[3];
    const float* k_intra = (const float*)d_in[4];
    const float* v_intra = (const float*)d_in[5];
    float* out = (float*)d_out;
    float* wsI = (float*)d_ws;                      // V_inter: [16,32,8,64]  = 1 MiB
    float* wsT = wsI + (size_t)16 * 32 * NH * NE;   // V_intra: [16,128,8,64] = 4 MiB

    // Inter attention -> wsI. Grid = B*H = 128 blocks.
    attn_kernel<32><<<16 * 8, 256, 0, stream>>>(q_inter, k_inter, v_inter, wsI);

    // Intra attention -> wsT. Grid = B*H*4 = 512 blocks.
    attn_kernel<128><<<16 * 8 * 4, 256, 0, stream>>>(q_intra, k_intra, v_intra, wsT);

    // Upsample + add -> out. 8192 blocks x 256 threads, 4 float4/thread.
    upsample_add_kernel<<<8192, 256, 0, stream>>>(
        (const float4*)wsI, (const float4*)wsT, (float4*)out);
}

// Round 3
// 191.241 us; speedup vs baseline: 1.0176x; 1.0176x over previous
//
#include <hip/hip_runtime.h>

// Problem: B=16, PATCH_NUM=32, PATCH_SIZE=128, H=8, E=64, WIN=4096
// out[b,l,h,e] = V_inter[b, l>>7, h, e] + V_intra[b, l>>5, h, e]
// V_* are full-softmax attentions (scale = 1/8) over L=32 / L=128.
//
// Round 2 -> 3:
//  * score phase: thread now owns CONSECUTIVE score cols (c = cg + j*32);
//    K-row LDS stride 68 (== 4 mod 32) -> 4-way max conflict instead of the
//    16-way from the old c0=cg*CPT stride-272 pattern.
//  * V tile unpadded (VST=64): PV reads are broadcast/2-way (free), staging
//    writes contiguous.
//  * upsample: 32 consecutive output rows share one sum -> compute once in
//    registers, duplicate-store; read traffic 256 MiB -> ~8 MiB.

#define NH 8
#define NE 64
#define ROWSTRIDE (NH * NE)   // 512 floats between consecutive l for fixed (b,h)

__device__ __forceinline__ float dot4(const float4 a, const float4 b) {
    return a.x * b.x + a.y * b.y + a.z * b.z + a.w * b.w;
}

// One block = (b, h, tile-of-32-query-rows), 256 threads.
// Writes its 32 attention-output rows to dst[B, L, H, E] (compact).
template <int L>
__global__ __launch_bounds__(256) void attn_kernel(
    const float* __restrict__ qg_, const float* __restrict__ kg_,
    const float* __restrict__ vg_, float* __restrict__ dst)
{
    constexpr int TILES = L / 32;   // row tiles per (b,h)
    constexpr int CPT   = L / 32;   // score cols per thread
    constexpr int SST   = L + 1;    // score row stride
    constexpr int KST   = 68;       // K row stride: 68 mod 32 == 4 -> 4-way max
    constexpr int QST   = 68;       // Q row stride (reads are broadcast anyway)
    constexpr int VST   = 64;       // V row stride: reads broadcast/2-way, no pad

    __shared__ __align__(16) float Ks[L * KST];
    __shared__ __align__(16) float Vs[L * VST];
    __shared__ __align__(16) float Qs[32 * QST];
    __shared__ float S[32 * SST];

    const int tid  = threadIdx.x;
    const int bid  = blockIdx.x;
    const int tile = bid % TILES;
    const int h    = (bid / TILES) % NH;
    const int b    = bid / (TILES * NH);
    const int r0   = tile * 32;

    const float* kg = kg_ + ((size_t)b * L * NH + h) * NE;
    const float* vg = vg_ + ((size_t)b * L * NH + h) * NE;
    const float* qg = qg_ + ((size_t)(b * L + r0) * NH + h) * NE;

    // ---- stage K, V (all L rows) and Q (32 rows) into LDS ----
    for (int idx = tid; idx < L * 16; idx += 256) {
        const int row = idx >> 4;
        const int f   = (idx & 15) * 4;
        *(float4*)&Ks[row * KST + f] = *(const float4*)(kg + (size_t)row * ROWSTRIDE + f);
        *(float4*)&Vs[row * VST + f] = *(const float4*)(vg + (size_t)row * ROWSTRIDE + f);
    }
    for (int idx = tid; idx < 32 * 16; idx += 256) {
        const int row = idx >> 4;
        const int f   = (idx & 15) * 4;
        *(float4*)&Qs[row * QST + f] = *(const float4*)(qg + (size_t)row * ROWSTRIDE + f);
    }
    __syncthreads();

    // ---- scores: 32 rows x L cols; thread (rg,cg) = rows rg*4..+3,
    //      cols {cg + j*32 : j<CPT} (consecutive rows across lanes) ----
    {
        const int rg = tid >> 5;        // 0..7
        const int cg = tid & 31;        // 0..31
        const int rr = rg * 4;
        float acc[4][CPT];
        #pragma unroll
        for (int i = 0; i < 4; i++)
            #pragma unroll
            for (int j = 0; j < CPT; j++) acc[i][j] = 0.f;

        #pragma unroll
        for (int e = 0; e < NE; e += 4) {
            float4 qv[4], kv[CPT];
            #pragma unroll
            for (int i = 0; i < 4; i++) qv[i] = *(const float4*)&Qs[(rr + i) * QST + e];
            #pragma unroll
            for (int j = 0; j < CPT; j++) kv[j] = *(const float4*)&Ks[(cg + j * 32) * KST + e];
            #pragma unroll
            for (int i = 0; i < 4; i++)
                #pragma unroll
                for (int j = 0; j < CPT; j++)
                    acc[i][j] += dot4(qv[i], kv[j]);
        }
        #pragma unroll
        for (int i = 0; i < 4; i++)
            #pragma unroll
            for (int j = 0; j < CPT; j++)
                S[(rr + i) * SST + cg + j * 32] = acc[i][j] * 0.125f;  // 1/sqrt(64)
    }
    __syncthreads();

    // ---- softmax: thread (r = tid>>3, sub = tid&7); redundant row scans
    //      (reads broadcast across the 8 subs -> conflict-free) ----
    const int r   = tid >> 3;
    const int sub = tid & 7;
    float m = -1e30f;
    for (int c = 0; c < L; c++) m = fmaxf(m, S[r * SST + c]);
    float sum = 0.f;
    for (int c = 0; c < L; c++) sum += __expf(S[r * SST + c] - m);
    const float inv = 1.f / sum;
    __syncthreads();              // everyone done reading raw scores
    for (int c = sub; c < L; c += 8)
        S[r * SST + c] = __expf(S[r * SST + c] - m);   // unnormalized p
    __syncthreads();

    // ---- PV: thread (r, sub) computes out[r][e0..e0+7] ----
    const int e0 = sub * 8;
    float a0=0,a1=0,a2=0,a3=0,a4=0,a5=0,a6=0,a7=0;
    for (int c = 0; c < L; c++) {
        const float p  = S[r * SST + c];
        const float4 va = *(const float4*)&Vs[c * VST + e0];
        const float4 vb = *(const float4*)&Vs[c * VST + e0 + 4];
        a0 += p * va.x; a1 += p * va.y; a2 += p * va.z; a3 += p * va.w;
        a4 += p * vb.x; a5 += p * vb.y; a6 += p * vb.z; a7 += p * vb.w;
    }
    const float4 oA = make_float4(a0 * inv, a1 * inv, a2 * inv, a3 * inv);
    const float4 oB = make_float4(a4 * inv, a5 * inv, a6 * inv, a7 * inv);

    float* w = dst + ((size_t)(b * L + r0 + r) * NH + h) * NE + e0;
    *(float4*)w       = oA;
    *(float4*)(w + 4) = oB;
}

// Thread t = (((b*32+pn)*4+g)*8+h)*16+e4 computes
//   s = wsI[b,pn,h,e4] + wsT[b,pn*4+g,h,e4]   (one value)
// and stores it to the 32 output rows l = pn*128 + g*32 + j.
// Wave lanes span (h,e4) -> every store instruction is 64 consecutive
// float4s = 1 KB contiguous. Reads: ~8 MiB total (vs 256 MiB before).
__global__ __launch_bounds__(256) void upsample_add_kernel(
    const float4* __restrict__ wsI, const float4* __restrict__ wsT,
    float4* __restrict__ out)
{
    const int t  = blockIdx.x * 256 + threadIdx.x;   // 0 .. 262143
    const int e4 = t & 15;
    const int h  = (t >> 4) & 7;
    const int g  = (t >> 7) & 3;
    const int pn = (t >> 9) & 31;
    const int b  = t >> 14;

    const float4 a = wsI[((b * 32 + pn) * NH + h) * 16 + e4];
    const float4 c = wsT[((b * 128 + pn * 4 + g) * NH + h) * 16 + e4];
    const float4 s = make_float4(a.x + c.x, a.y + c.y, a.z + c.z, a.w + c.w);

    float4* o = out + ((((size_t)b * 4096 + pn * 128 + g * 32) * NH + h) * 16 + e4);
    #pragma unroll
    for (int j = 0; j < 32; j++)
        o[(size_t)j * (ROWSTRIDE / 4)] = s;   // next l: +512 floats = +128 float4
}

extern "C" void kernel_launch(void* const* d_in, const int* in_sizes, int n_in,
                              void* d_out, int out_size, void* d_ws, size_t ws_size,
                              hipStream_t stream) {
    const float* q_inter = (const float*)d_in[0];
    const float* k_inter = (const float*)d_in[1];
    const float* v_inter = (const float*)d_in[2];
    const float* q_intra = (const float*)d_in[3];
    const float* k_intra = (const float*)d_in[4];
    const float* v_intra = (const float*)d_in[5];
    float* out = (float*)d_out;
    float* wsI = (float*)d_ws;                      // V_inter: [16,32,8,64]  = 1 MiB
    float* wsT = wsI + (size_t)16 * 32 * NH * NE;   // V_intra: [16,128,8,64] = 4 MiB

    // Inter attention -> wsI. Grid = B*H = 128 blocks.
    attn_kernel<32><<<16 * 8, 256, 0, stream>>>(q_inter, k_inter, v_inter, wsI);

    // Intra attention -> wsT. Grid = B*H*4 = 512 blocks.
    attn_kernel<128><<<16 * 8 * 4, 256, 0, stream>>>(q_intra, k_intra, v_intra, wsT);

    // Upsample + add -> out. 262144 threads, 32 duplicated stores each.
    upsample_add_kernel<<<1024, 256, 0, stream>>>(
        (const float4*)wsI, (const float4*)wsT, (float4*)out);
}

// Round 4
// 183.995 us; speedup vs baseline: 1.0577x; 1.0394x over previous
//
#include <hip/hip_runtime.h>

// Problem: B=16, PATCH_NUM=32, PATCH_SIZE=128, H=8, E=64, WIN=4096
// out[b,l,h,e] = V_inter[b, l>>7, h, e] + V_intra[b, l>>5, h, e]
// V_* are full-softmax attentions (scale = 1/8) over L=32 / L=128.
//
// Round 3 -> 4:
//  * softmax moved to registers (__shfl_xor butterflies over the 32-lane
//    half-wave that owns a row); score matrix S aliased into the dead Ks
//    buffer -> LDS 92.8 KB -> 74.5 KB -> 2 blocks/CU (8 waves, was 4).
//  * attn32 + attn128 fused into one 640-block kernel (4:1 interleave).
//  * PV reads p as aligned float4 (SST = L+4 = 4 mod 32).
//  * upsample uses nontemporal stores (pure streaming writes).

#define NH 8
#define NE 64
#define ROWSTRIDE (NH * NE)   // 512 floats between consecutive l for fixed (b,h)

typedef float vf4 __attribute__((ext_vector_type(4)));

__device__ __forceinline__ float dot4(const float4 a, const float4 b) {
    return a.x * b.x + a.y * b.y + a.z * b.z + a.w * b.w;
}

// One logical block = (b, h, tile-of-32-query-rows), 256 threads.
// Writes 32 attention-output rows to dst[B, L, H, E] (compact).
template <int L>
__device__ __forceinline__ void attn_block(
    const int bid, const float* __restrict__ qg_, const float* __restrict__ kg_,
    const float* __restrict__ vg_, float* __restrict__ dst,
    float* sKs, float* sVs, float* sQs)
{
    constexpr int TILES = L / 32;   // row tiles per (b,h)
    constexpr int CPT   = L / 32;   // score cols per thread
    constexpr int SST   = L + 4;    // S row stride: ==4 mod 32, rows 16B-aligned
    constexpr int KST   = 68;       // K row stride: ==4 mod 32 -> 4-way max (1.58x)
    constexpr int QST   = 68;       // Q row stride (reads broadcast anyway)
    constexpr int VST   = 64;       // V row stride: reads broadcast/2-way (free)

    const int tid  = threadIdx.x;
    const int tile = bid % TILES;
    const int h    = (bid / TILES) % NH;
    const int b    = bid / (TILES * NH);
    const int r0   = tile * 32;

    const float* kg = kg_ + ((size_t)b * L * NH + h) * NE;
    const float* vg = vg_ + ((size_t)b * L * NH + h) * NE;
    const float* qg = qg_ + ((size_t)(b * L + r0) * NH + h) * NE;

    // ---- stage K, V (all L rows) and Q (32 rows) into LDS ----
    for (int idx = tid; idx < L * 16; idx += 256) {
        const int row = idx >> 4;
        const int f   = (idx & 15) * 4;
        *(float4*)&sKs[row * KST + f] = *(const float4*)(kg + (size_t)row * ROWSTRIDE + f);
        *(float4*)&sVs[row * VST + f] = *(const float4*)(vg + (size_t)row * ROWSTRIDE + f);
    }
    for (int idx = tid; idx < 32 * 16; idx += 256) {
        const int row = idx >> 4;
        const int f   = (idx & 15) * 4;
        *(float4*)&sQs[row * QST + f] = *(const float4*)(qg + (size_t)row * ROWSTRIDE + f);
    }
    __syncthreads();

    // ---- scores in registers: thread (rg,cg) owns rows rg*4..+3,
    //      cols {cg + 32j : j < CPT} ----
    const int rg = tid >> 5;        // 0..7 (half-wave id within block)
    const int cg = tid & 31;        // 0..31
    const int rr = rg * 4;
    float acc[4][CPT];
    #pragma unroll
    for (int i = 0; i < 4; i++)
        #pragma unroll
        for (int j = 0; j < CPT; j++) acc[i][j] = 0.f;

    #pragma unroll
    for (int e = 0; e < NE; e += 4) {
        float4 qv[4], kv[CPT];
        #pragma unroll
        for (int i = 0; i < 4; i++) qv[i] = *(const float4*)&sQs[(rr + i) * QST + e];
        #pragma unroll
        for (int j = 0; j < CPT; j++) kv[j] = *(const float4*)&sKs[(cg + j * 32) * KST + e];
        #pragma unroll
        for (int i = 0; i < 4; i++)
            #pragma unroll
            for (int j = 0; j < CPT; j++)
                acc[i][j] += dot4(qv[i], kv[j]);
    }
    __syncthreads();                // all K reads done; Ks space is dead now

    float* S = sKs;                 // alias S into the dead Ks buffer

    // ---- softmax in registers: row's 32..128 cols live across the 32 lanes
    //      of this half-wave (shfl_xor masks 1..16 stay inside it) ----
    #pragma unroll
    for (int i = 0; i < 4; i++) {
        float m = acc[i][0] * 0.125f;
        #pragma unroll
        for (int j = 1; j < CPT; j++) m = fmaxf(m, acc[i][j] * 0.125f);
        #pragma unroll
        for (int msk = 1; msk < 32; msk <<= 1) m = fmaxf(m, __shfl_xor(m, msk));
        float p[CPT], s = 0.f;
        #pragma unroll
        for (int j = 0; j < CPT; j++) { p[j] = __expf(acc[i][j] * 0.125f - m); s += p[j]; }
        #pragma unroll
        for (int msk = 1; msk < 32; msk <<= 1) s += __shfl_xor(s, msk);
        const float inv = 1.f / s;
        #pragma unroll
        for (int j = 0; j < CPT; j++)
            S[(rr + i) * SST + cg + 32 * j] = p[j] * inv;   // normalized p
    }
    __syncthreads();

    // ---- PV: thread (r, sub) computes out[r][e0..e0+7] ----
    const int r   = tid >> 3;
    const int sub = tid & 7;
    const int e0  = sub * 8;
    float a0=0,a1=0,a2=0,a3=0,a4=0,a5=0,a6=0,a7=0;
    for (int c0 = 0; c0 < L; c0 += 4) {
        const float4 p4 = *(const float4*)&S[r * SST + c0];   // aligned: SST%4==0
        const float pv[4] = { p4.x, p4.y, p4.z, p4.w };
        #pragma unroll
        for (int u = 0; u < 4; u++) {
            const float p  = pv[u];
            const float4 va = *(const float4*)&sVs[(c0 + u) * VST + e0];
            const float4 vb = *(const float4*)&sVs[(c0 + u) * VST + e0 + 4];
            a0 += p * va.x; a1 += p * va.y; a2 += p * va.z; a3 += p * va.w;
            a4 += p * vb.x; a5 += p * vb.y; a6 += p * vb.z; a7 += p * vb.w;
        }
    }
    float* w = dst + ((size_t)(b * L + r0 + r) * NH + h) * NE + e0;
    *(float4*)w       = make_float4(a0, a1, a2, a3);
    *(float4*)(w + 4) = make_float4(a4, a5, a6, a7);
}

// 640 blocks: group g of 5 = 4 intra (L=128) blocks + 1 inter (L=32) block.
// LDS = (128*68 + 128*64 + 32*68) * 4 B = 74.5 KB -> 2 blocks/CU.
__global__ __launch_bounds__(256, 2) void attn_fused(
    const float* __restrict__ qI, const float* __restrict__ kI, const float* __restrict__ vI,
    const float* __restrict__ qT, const float* __restrict__ kT, const float* __restrict__ vT,
    float* __restrict__ wsI, float* __restrict__ wsT)
{
    __shared__ __align__(16) float sKs[128 * 68];
    __shared__ __align__(16) float sVs[128 * 64];
    __shared__ __align__(16) float sQs[32 * 68];

    const int bid = blockIdx.x;
    const int grp = bid / 5;
    const int rem = bid - grp * 5;
    if (rem < 4)
        attn_block<128>(grp * 4 + rem, qT, kT, vT, wsT, sKs, sVs, sQs);
    else
        attn_block<32>(grp, qI, kI, vI, wsI, sKs, sVs, sQs);
}

// Thread t = (((b*32+pn)*4+g)*8+h)*16+e4 computes
//   s = wsI[b,pn,h,e4] + wsT[b,pn*4+g,h,e4]
// once and streams it to the 32 output rows l = pn*128 + g*32 + j.
// Wave lanes span (h,e4) -> each store instr is 1 KB contiguous; nontemporal.
__global__ __launch_bounds__(256) void upsample_add_kernel(
    const float4* __restrict__ wsI, const float4* __restrict__ wsT,
    float* __restrict__ out)
{
    const int t  = blockIdx.x * 256 + threadIdx.x;   // 0 .. 262143
    const int e4 = t & 15;
    const int h  = (t >> 4) & 7;
    const int g  = (t >> 7) & 3;
    const int pn = (t >> 9) & 31;
    const int b  = t >> 14;

    const float4 a = wsI[((b * 32 + pn) * NH + h) * 16 + e4];
    const float4 c = wsT[((b * 128 + pn * 4 + g) * NH + h) * 16 + e4];
    vf4 s;
    s.x = a.x + c.x; s.y = a.y + c.y; s.z = a.z + c.z; s.w = a.w + c.w;

    float* o = out + ((((size_t)b * 4096 + pn * 128 + g * 32) * NH + h) * 16 + e4) * 4;
    #pragma unroll
    for (int j = 0; j < 32; j++)
        __builtin_nontemporal_store(s, (vf4*)(o + (size_t)j * ROWSTRIDE));
}

extern "C" void kernel_launch(void* const* d_in, const int* in_sizes, int n_in,
                              void* d_out, int out_size, void* d_ws, size_t ws_size,
                              hipStream_t stream) {
    const float* q_inter = (const float*)d_in[0];
    const float* k_inter = (const float*)d_in[1];
    const float* v_inter = (const float*)d_in[2];
    const float* q_intra = (const float*)d_in[3];
    const float* k_intra = (const float*)d_in[4];
    const float* v_intra = (const float*)d_in[5];
    float* out = (float*)d_out;
    float* wsI = (float*)d_ws;                      // V_inter: [16,32,8,64]  = 1 MiB
    float* wsT = wsI + (size_t)16 * 32 * NH * NE;   // V_intra: [16,128,8,64] = 4 MiB

    // Both attentions in one launch: 128*5 = 640 blocks (4 intra : 1 inter).
    attn_fused<<<640, 256, 0, stream>>>(
        q_inter, k_inter, v_inter, q_intra, k_intra, v_intra, wsI, wsT);

    // Upsample + add -> out. 262144 threads, 32 streaming stores each.
    upsample_add_kernel<<<1024, 256, 0, stream>>>(
        (const float4*)wsI, (const float4*)wsT, out);
}